// Round 15
// baseline (203.580 us; speedup 1.0000x reference)
//
#include <hip/hip_runtime.h>

#define LLEN 65536
#define CIN 64
#define COUT 64
#define BPW 1024            // bitplane words per (b,ci) row
#define CHUNK 2048          // l per B-block
#define NTILE (CHUNK / 64 + 2)   // 34 transpose tiles (incl. 2 halo)

typedef float f32x4 __attribute__((ext_vector_type(4)));
typedef unsigned long long u64;

// Per-co constant record, 64 B -> one s_load_dwordx16.
struct __align__(64) WRec {
    u64 p0, p1, p2;                 // sign words (bit=1 iff w>0) for k=0,1,2
    float A;    // wscale * sum_nnz + bias
    float S;    // -2 * wscale
    float Bv, G, Z;                 // RPReLU beta, gamma, zeta
    float f0, f2;                   // 0.5*nnz(k=0), 0.5*nnz(k=2) edge fixups
    float pad[3];
};

__device__ __forceinline__ void pack_weights_body(
        const float* __restrict__ w, const float* __restrict__ wscale,
        const float* __restrict__ bias, const float* __restrict__ beta,
        const float* __restrict__ gamma, const float* __restrict__ zeta,
        WRec* __restrict__ rec) {
    int co = threadIdx.x;
    if (co >= COUT) return;
    const float* wr = w + co * (CIN * 3);
    u64 p[3] = {0, 0, 0}, nzw[3] = {0, 0, 0};
    #pragma unroll
    for (int q = 0; q < 4; ++q) {
        f32x4 buf[12];
        #pragma unroll
        for (int j = 0; j < 12; ++j)
            buf[j] = *(const f32x4*)(wr + q * 48 + 4 * j);
        #pragma unroll
        for (int j = 0; j < 12; ++j) {
            #pragma unroll
            for (int m = 0; m < 4; ++m) {
                const int idx = q * 48 + 4 * j + m;   // compile-time constant
                const int ci = idx / 3, k = idx % 3;
                const float wv = buf[j][m];
                p[k]   |= ((u64)(wv > 0.0f)) << ci;
                nzw[k] |= ((u64)(wv != 0.0f)) << ci;
            }
        }
    }
    const int n0 = __popcll(nzw[0]), n1 = __popcll(nzw[1]), n2 = __popcll(nzw[2]);
    WRec r;
    float s = wscale[co];
    r.p0 = p[0]; r.p1 = p[1]; r.p2 = p[2];
    r.A  = s * (float)(n0 + n1 + n2) + bias[co];
    r.S  = -2.0f * s;
    r.Bv = beta[co]; r.G = gamma[co]; r.Z = zeta[co];
    r.f0 = 0.5f * (float)n0;
    r.f2 = 0.5f * (float)n2;
    r.pad[0] = r.pad[1] = r.pad[2] = 0.0f;
    rec[co] = r;
}

// ---------------------------------------------------------------------------
// Kernel A: bitplane pack. Block = one (b,ci) row (256 KB), 4 waves, each
// wave reads its 64 KB quarter FULLY SEQUENTIALLY (dword/lane = 256 B/instr).
// __ballot over 64 consecutive-l lanes = one bitplane word; 64 ballots are
// lane-selected into a register, then one coalesced 512 B store per group.
// Extra block (x==CIN, y==0) folds the weight pack.
// ---------------------------------------------------------------------------
__global__ void __launch_bounds__(256) pack_bitplane(
        const float* __restrict__ x, const float* __restrict__ alpha,
        u64* __restrict__ bp,
        const float* __restrict__ w, const float* __restrict__ wscale,
        const float* __restrict__ bias, const float* __restrict__ beta,
        const float* __restrict__ gamma, const float* __restrict__ zeta,
        WRec* __restrict__ rec) {
    if (blockIdx.x == CIN) {
        if (blockIdx.y == 0)
            pack_weights_body(w, wscale, bias, beta, gamma, zeta, rec);
        return;
    }
    const int lane = threadIdx.x & 63;
    const int wv   = threadIdx.x >> 6;
    const int ci = blockIdx.x, b = blockIdx.y;
    const float a = alpha[ci];                       // wave-uniform scalar
    const float* xr = x + ((size_t)b * CIN + ci) * LLEN + wv * 16384;
    u64* bpr = bp + ((size_t)b * CIN + ci) * BPW + wv * 256;

    #pragma unroll
    for (int g = 0; g < 4; ++g) {
        u64 acc = 0;
        #pragma unroll
        for (int s = 0; s < 64; ++s) {
            float v = __builtin_nontemporal_load(xr + g * 4096 + s * 64 + lane);
            u64 bal = __ballot(v >= a);              // word(base + 64s), bit=lane=l
            if (lane == s) acc = bal;                // 2 cndmask
        }
        bpr[g * 64 + lane] = acc;                    // lane j = word idx +j, 512 B
    }
}

__device__ __forceinline__ float rprelu(float y, float B, float G, float Z) {
    float xs = y - G;
    return (y > G) ? (xs + Z) : fmaf(B, xs, Z);
}

__device__ __forceinline__ u64 xstep(u64 v, u64 y, int lane, int d, u64 m) {
    return ((lane & d) == 0) ? ((v & m) | ((y & m) << d))
                             : ((v & ~m) | ((y >> d) & m));
}

// ---------------------------------------------------------------------------
// Kernel B: transpose + compute. Block = (2048-l chunk, b), 512 threads.
// Stage 1: 34 tiles; wave loads lane=ci bitplane word, 6-stage shfl_xor
// butterfly transpose -> lane j holds word-form word(64W+j) -> LDS (padded
// index lp+(lp>>2)). Stage 2: thread loads its 6-word window to registers
// once, sweeps 64 co, nt f32x4 stores (8 KB runs per co).
// ---------------------------------------------------------------------------
__global__ void __launch_bounds__(512) bconv2(
        const u64* __restrict__ bp, const WRec* __restrict__ rec,
        float* __restrict__ out) {
    __shared__ u64 wlds[NTILE * 64 + ((NTILE * 64) >> 2) + 2];
    const int t = threadIdx.x;
    const int lane = t & 63, wv = t >> 6;            // 8 waves
    const int chunk = blockIdx.x, b = blockIdx.y;
    const int c0 = chunk * CHUNK;
    const int W0 = c0 / 64 - 1;                      // may be -1

    for (int T = wv; T < NTILE; T += 8) {
        const int W = W0 + T;
        u64 v = 0;
        if (W >= 0 && W < BPW)
            v = bp[((size_t)b * CIN + lane) * BPW + W];
        u64 y;
        y = (u64)__shfl_xor((long long)v, 32); v = xstep(v, y, lane, 32, 0x00000000FFFFFFFFull);
        y = (u64)__shfl_xor((long long)v, 16); v = xstep(v, y, lane, 16, 0x0000FFFF0000FFFFull);
        y = (u64)__shfl_xor((long long)v,  8); v = xstep(v, y, lane,  8, 0x00FF00FF00FF00FFull);
        y = (u64)__shfl_xor((long long)v,  4); v = xstep(v, y, lane,  4, 0x0F0F0F0F0F0F0F0Full);
        y = (u64)__shfl_xor((long long)v,  2); v = xstep(v, y, lane,  2, 0x3333333333333333ull);
        y = (u64)__shfl_xor((long long)v,  1); v = xstep(v, y, lane,  1, 0x5555555555555555ull);
        const int lp = T * 64 + lane;                // lpos = l - (c0-64)
        wlds[lp + (lp >> 2)] = v;                    // coalesced, 2-way max
    }
    __syncthreads();

    // Stage 2: thread owns l = c0 + 4t .. +3; window words lpos 4t+63 .. 4t+68
    u64 xq[6];
    #pragma unroll
    for (int k = 0; k < 6; ++k) {
        const int lp = 4 * t + 63 + k;
        xq[k] = wlds[lp + (lp >> 2)];
    }
    const bool lo = (chunk == 0) && (t == 0);                 // l==0
    const bool hi = (chunk == gridDim.x - 1) && (t == 511);   // l==LLEN-1
    float* outp = out + (size_t)b * COUT * LLEN + c0 + 4 * t;

    #pragma unroll 4
    for (int co = 0; co < COUT; ++co) {
        const WRec r = rec[co];                      // uniform -> s_load
        float fx = (float)(__popcll(xq[0] ^ r.p0) + __popcll(xq[1] ^ r.p1)
                         + __popcll(xq[2] ^ r.p2));
        float fy = (float)(__popcll(xq[1] ^ r.p0) + __popcll(xq[2] ^ r.p1)
                         + __popcll(xq[3] ^ r.p2));
        float fz = (float)(__popcll(xq[2] ^ r.p0) + __popcll(xq[3] ^ r.p1)
                         + __popcll(xq[4] ^ r.p2));
        float fw = (float)(__popcll(xq[3] ^ r.p0) + __popcll(xq[4] ^ r.p1)
                         + __popcll(xq[5] ^ r.p2));
        if (lo)   // l==0: k=0 term is zero padding
            fx = (float)(__popcll(xq[1] ^ r.p1) + __popcll(xq[2] ^ r.p2)) + r.f0;
        if (hi)   // l==LLEN-1: k=2 term is zero padding
            fw = (float)(__popcll(xq[3] ^ r.p0) + __popcll(xq[4] ^ r.p1)) + r.f2;
        f32x4 o;
        o.x = rprelu(fmaf(r.S, fx, r.A), r.Bv, r.G, r.Z);
        o.y = rprelu(fmaf(r.S, fy, r.A), r.Bv, r.G, r.Z);
        o.z = rprelu(fmaf(r.S, fz, r.A), r.Bv, r.G, r.Z);
        o.w = rprelu(fmaf(r.S, fw, r.A), r.Bv, r.G, r.Z);
        __builtin_nontemporal_store(o, (f32x4*)(outp + (size_t)co * LLEN));
    }
}

extern "C" void kernel_launch(void* const* d_in, const int* in_sizes, int n_in,
                              void* d_out, int out_size, void* d_ws, size_t ws_size,
                              hipStream_t stream) {
    const float* x      = (const float*)d_in[0];
    const float* alpha  = (const float*)d_in[1];
    const float* w      = (const float*)d_in[2];
    const float* wscale = (const float*)d_in[3];
    const float* bias   = (const float*)d_in[4];
    const float* beta   = (const float*)d_in[5];
    const float* gamma  = (const float*)d_in[6];
    const float* zeta   = (const float*)d_in[7];
    float* out = (float*)d_out;

    // ws: [0,4KB) WRec[64]; [4KB, 4KB + 16*64*1024*8 = 8 MB) bitplanes.
    WRec* rec = (WRec*)d_ws;
    u64* bp = (u64*)((char*)d_ws + 4096);

    dim3 gridA(CIN + 1, 16);   // +1 block: weight pack
    pack_bitplane<<<gridA, 256, 0, stream>>>(x, alpha, bp, w, wscale, bias,
                                             beta, gamma, zeta, rec);

    dim3 gridB(LLEN / CHUNK, 16);   // (chunk, b)
    bconv2<<<gridB, 512, 0, stream>>>(bp, rec, out);
}

// Round 16
// 102.796 us; speedup vs baseline: 1.9804x; 1.9804x over previous
//
#include <hip/hip_runtime.h>

#define LLEN 65536
#define CIN 64
#define COUT 64
// bits row: word(l) stored at position l+4; rows (LLEN+8) u64 = 32B-aligned.
// Positions 0..3 and LLEN+4..LLEN+7 are never written (EDGE fixups ignore).
#define BROW (LLEN + 8)
#define NBLK_A (LLEN / 2048)   // 32 data blocks per batch row

typedef float f32x4 __attribute__((ext_vector_type(4)));
typedef unsigned long long u64;
typedef u64 u64x4 __attribute__((ext_vector_type(4)));

// Per-co constant record, 64 B so the per-block fetch is one s_load_dwordx16.
struct __align__(64) WRec {
    u64 p0, p1, p2;                 // sign words (bit=1 iff w>0) for k=0,1,2
    float A;    // wscale * sum_nnz + bias
    float S;    // -2 * wscale
    float Bv, G, Z;                 // RPReLU beta, gamma, zeta
    float f0, f2;                   // 0.5*nnz(k=0), 0.5*nnz(k=2) edge fixups
    float pad[3];
};

__device__ __forceinline__ void pack_weights_body(
        const float* __restrict__ w, const float* __restrict__ wscale,
        const float* __restrict__ bias, const float* __restrict__ beta,
        const float* __restrict__ gamma, const float* __restrict__ zeta,
        WRec* __restrict__ rec) {
    int co = threadIdx.x;
    if (co >= COUT) return;
    const float* wr = w + co * (CIN * 3);
    u64 p[3] = {0, 0, 0}, nzw[3] = {0, 0, 0};
    #pragma unroll
    for (int q = 0; q < 4; ++q) {
        f32x4 buf[12];
        #pragma unroll
        for (int j = 0; j < 12; ++j)
            buf[j] = *(const f32x4*)(wr + q * 48 + 4 * j);
        #pragma unroll
        for (int j = 0; j < 12; ++j) {
            #pragma unroll
            for (int m = 0; m < 4; ++m) {
                const int idx = q * 48 + 4 * j + m;   // compile-time constant
                const int ci = idx / 3, k = idx % 3;
                const float wv = buf[j][m];
                p[k]   |= ((u64)(wv > 0.0f)) << ci;
                nzw[k] |= ((u64)(wv != 0.0f)) << ci;
            }
        }
    }
    const int n0 = __popcll(nzw[0]), n1 = __popcll(nzw[1]), n2 = __popcll(nzw[2]);
    WRec r;
    float s = wscale[co];
    r.p0 = p[0]; r.p1 = p[1]; r.p2 = p[2];
    r.A  = s * (float)(n0 + n1 + n2) + bias[co];
    r.S  = -2.0f * s;
    r.Bv = beta[co]; r.G = gamma[co]; r.Z = zeta[co];
    r.f0 = 0.5f * (float)n0;
    r.f2 = 0.5f * (float)n2;
    r.pad[0] = r.pad[1] = r.pad[2] = 0.0f;
    rec[co] = r;
}

// ---------------------------------------------------------------------------
// Kernel A: streaming pack. Block = (2048-l tile, b) -> per-ci segment is
// 8 KB. Thread owns 8 l as two 16 B lanes-coalesced f32x4 loads per row
// (at +4t and +1024+4t), nontemporal (x is read-once; keep L3 clean).
// Loads batched 4 rows x 2 = 8 in flight. Extra block (x==NBLK_A, y==0)
// folds the weight pack (no serial launch tail).
// ---------------------------------------------------------------------------
__global__ void __launch_bounds__(256) pack_x(
        const float* __restrict__ x,
        const float* __restrict__ alpha,
        u64* __restrict__ bits,
        const float* __restrict__ w,
        const float* __restrict__ wscale,
        const float* __restrict__ bias,
        const float* __restrict__ beta,
        const float* __restrict__ gamma,
        const float* __restrict__ zeta,
        WRec* __restrict__ rec) {
    if (blockIdx.x == NBLK_A) {
        if (blockIdx.y == 0)
            pack_weights_body(w, wscale, bias, beta, gamma, zeta, rec);
        return;
    }
    const int t = threadIdx.x;
    const int b = blockIdx.y;
    const int l0 = blockIdx.x * 2048;
    const float* xb = x + (size_t)b * CIN * LLEN + l0 + 4 * t;

    u64 wa0 = 0, wa1 = 0, wa2 = 0, wa3 = 0;   // words for l0+4t..+3
    u64 wb0 = 0, wb1 = 0, wb2 = 0, wb3 = 0;   // words for l0+1024+4t..+3
    #pragma unroll
    for (int q = 0; q < 16; ++q) {
        f32x4 blo[4], bhi[4];
        #pragma unroll
        for (int j = 0; j < 4; ++j) {
            const float* rp = xb + (size_t)(q * 4 + j) * LLEN;
            blo[j] = __builtin_nontemporal_load((const f32x4*)rp);
            bhi[j] = __builtin_nontemporal_load((const f32x4*)(rp + 1024));
        }
        #pragma unroll
        for (int j = 0; j < 4; ++j) {
            const int ci = q * 4 + j;
            const float a = alpha[ci];             // uniform -> s_load
            wa0 |= ((u64)(blo[j].x >= a)) << ci;
            wa1 |= ((u64)(blo[j].y >= a)) << ci;
            wa2 |= ((u64)(blo[j].z >= a)) << ci;
            wa3 |= ((u64)(blo[j].w >= a)) << ci;
            wb0 |= ((u64)(bhi[j].x >= a)) << ci;
            wb1 |= ((u64)(bhi[j].y >= a)) << ci;
            wb2 |= ((u64)(bhi[j].z >= a)) << ci;
            wb3 |= ((u64)(bhi[j].w >= a)) << ci;
        }
    }
    // word(l) at position l+4; (l0+4t+4) is a multiple of 4 -> 32 B aligned.
    u64* dst = bits + (size_t)b * BROW + l0 + 4 * t + 4;
    u64x4 va; va.x = wa0; va.y = wa1; va.z = wa2; va.w = wa3;
    u64x4 vb; vb.x = wb0; vb.y = wb1; vb.z = wb2; vb.w = wb3;
    *(u64x4*)dst = va;
    *(u64x4*)(dst + 1024) = vb;
}

__device__ __forceinline__ float rprelu(float y, float B, float G, float Z) {
    float xs = y - G;
    return (y > G) ? (xs + Z) : fmaf(B, xs, Z);
}

// ---------------------------------------------------------------------------
// Kernel B: compute + contiguous stream-out. Block = (chunk, co, b) with
// chunk INNERMOST: consecutive blocks write consecutive 32 KB -> sequential
// 256 KB write runs per (co,b); same-chunk co-blocks land on one XCD
// (id%8 == chunk%8) so each 66 KB bits segment is fetched to L2 once and
// reused 64x. WRec fetched once per block (SGPRs).
// Window for l: word(l-1)..word(l+4) = positions (l+3)..(l+8).
// ---------------------------------------------------------------------------
__global__ void __launch_bounds__(256) bconv_compute(
        const u64* __restrict__ bits,
        const WRec* __restrict__ rec,
        float* __restrict__ out) {
    const int t     = threadIdx.x;
    const int chunk = blockIdx.x;
    const int co    = blockIdx.y;
    const int b     = blockIdx.z;
    const int c0    = chunk * 8192;

    const WRec r = rec[co];                        // uniform -> s_load_dwordx16
    const u64* base = bits + (size_t)b * BROW + c0 + 4 * t;
    float* outp = out + ((size_t)b * COUT + co) * LLEN + c0 + 4 * t;

    const bool lo = (chunk == 0) && (t == 0);              // contains l==0
    const bool hi = (chunk == 7) && (t == 255);            // contains l==LLEN-1

    #pragma unroll 4
    for (int j = 0; j < 8; ++j) {
        const u64* src = base + 1024 * j;
        const u64 xq0 = src[3], xq1 = src[4], xq2 = src[5],
                  xq3 = src[6], xq4 = src[7], xq5 = src[8];

        float fx = (float)(__popcll(xq0 ^ r.p0) + __popcll(xq1 ^ r.p1)
                         + __popcll(xq2 ^ r.p2));
        float fy = (float)(__popcll(xq1 ^ r.p0) + __popcll(xq2 ^ r.p1)
                         + __popcll(xq3 ^ r.p2));
        float fz = (float)(__popcll(xq2 ^ r.p0) + __popcll(xq3 ^ r.p1)
                         + __popcll(xq4 ^ r.p2));
        float fw = (float)(__popcll(xq3 ^ r.p0) + __popcll(xq4 ^ r.p1)
                         + __popcll(xq5 ^ r.p2));
        if (j == 0 && lo)   // l==0: k=0 term is zero padding
            fx = (float)(__popcll(xq1 ^ r.p1) + __popcll(xq2 ^ r.p2)) + r.f0;
        if (j == 7 && hi)   // l==LLEN-1: k=2 term is zero padding
            fw = (float)(__popcll(xq3 ^ r.p0) + __popcll(xq4 ^ r.p1)) + r.f2;

        f32x4 o;
        o.x = rprelu(fmaf(r.S, fx, r.A), r.Bv, r.G, r.Z);
        o.y = rprelu(fmaf(r.S, fy, r.A), r.Bv, r.G, r.Z);
        o.z = rprelu(fmaf(r.S, fz, r.A), r.Bv, r.G, r.Z);
        o.w = rprelu(fmaf(r.S, fw, r.A), r.Bv, r.G, r.Z);
        __builtin_nontemporal_store(o, (f32x4*)(outp + 1024 * j));
    }
}

extern "C" void kernel_launch(void* const* d_in, const int* in_sizes, int n_in,
                              void* d_out, int out_size, void* d_ws, size_t ws_size,
                              hipStream_t stream) {
    const float* x      = (const float*)d_in[0];
    const float* alpha  = (const float*)d_in[1];
    const float* w      = (const float*)d_in[2];
    const float* wscale = (const float*)d_in[3];
    const float* bias   = (const float*)d_in[4];
    const float* beta   = (const float*)d_in[5];
    const float* gamma  = (const float*)d_in[6];
    const float* zeta   = (const float*)d_in[7];
    float* out = (float*)d_out;

    // ws layout: [0, 4KB) WRec[64]; [4KB, 4KB + 16*BROW*8) packed bits.
    WRec* rec = (WRec*)d_ws;
    u64* bits = (u64*)((char*)d_ws + 4096);

    dim3 gridA(NBLK_A + 1, 16);   // +1: weights block
    pack_x<<<gridA, 256, 0, stream>>>(x, alpha, bits, w, wscale, bias,
                                      beta, gamma, zeta, rec);

    dim3 gridB(8, COUT, 16);   // (chunk, co, b) — chunk inner: sequential writes
    bconv_compute<<<gridB, 256, 0, stream>>>(bits, rec, out);
}